// Round 13
// baseline (186.432 us; speedup 1.0000x reference)
//
#include <hip/hip_runtime.h>
#include <stdint.h>

// MultiHeadAttention: B=2,S=2048,D=1024,E=1024,H=16,DK=64. fp32 or bf16 I/O
// (runtime-sniffed), internal bf16 MFMA pipeline, fp32 accumulation.
// Round 13: GEMMs restructured to the flash-validated register-prefetch +
// double-buffered LDS + ONE barrier/iter shape (replaces m97's 2-barrier
// async16 shape whose vmcnt(0) drain exposes full load latency each iter).
// [Kc] fused converts  [K1] QKV NT-GEMM (128x128)  [K2] flash  [K3] out GEMM

typedef unsigned short u16;
typedef unsigned int u32;
typedef __attribute__((ext_vector_type(8))) short bf16x8;   // 8 bf16 = 4 VGPRs
typedef __attribute__((ext_vector_type(4))) float f32x4;
typedef __attribute__((ext_vector_type(4))) unsigned int u32x4;
typedef __attribute__((ext_vector_type(4))) unsigned short u16x4;
typedef __attribute__((ext_vector_type(2))) unsigned int u32x2;

#define LOG2E 1.44269504088896340736f
#define NSHIFT -17.312340490667562f          // -12 * LOG2E
#define QSCALE 0.18033688011112057f          // 0.125 * LOG2E

#if __has_builtin(__builtin_amdgcn_exp2f)
#define EXP2(x) __builtin_amdgcn_exp2f(x)    // raw v_exp_f32
#else
#define EXP2(x) exp2f(x)
#endif

static __device__ __forceinline__ float bf2f(u16 u) {
  union { u32 u; float f; } v; v.u = ((u32)u) << 16; return v.f;
}
static __device__ __forceinline__ u16 f2bf(float f) {        // RNE
  union { float f; u32 u; } v; v.f = f;
  return (u16)((v.u + 0x7FFFu + ((v.u >> 16) & 1u)) >> 16);
}
static __device__ __forceinline__ u32 pack2bf(u32 lo, u32 hi) {
  return __builtin_amdgcn_perm(hi, lo, 0x07060302u);  // {hi[31:16], lo[31:16]}
}

// inline dtype sniff from pristine x: fp32 -> even u16s are mantissa noise
static __device__ __forceinline__ bool sniff_f32(const u16* __restrict__ x) {
  const int lane = threadIdx.x & 63;
  const u16 v = x[lane * 2];
  const int e = (v >> 7) & 0xFF;
  const unsigned long long m = __ballot(e >= 100 && e <= 140);
  return __popcll(m) < 48;          // true = fp32 inputs
}

static __device__ __forceinline__ bf16x8 ld8cv(const void* p, size_t e, bool isf32) {
  bf16x8 r;
  if (isf32) {
    const u32x4 a = *(const u32x4*)((const float*)p + e);
    const u32x4 b = *(const u32x4*)((const float*)p + e + 4);
    u32* rr = (u32*)&r;
    rr[0] = pack2bf(a[0] + 0x8000u, a[1] + 0x8000u);
    rr[1] = pack2bf(a[2] + 0x8000u, a[3] + 0x8000u);
    rr[2] = pack2bf(b[0] + 0x8000u, b[1] + 0x8000u);
    rr[3] = pack2bf(b[2] + 0x8000u, b[3] + 0x8000u);
  } else {
    r = *(const bf16x8*)((const u16*)p + e);
  }
  return r;
}
static __device__ __forceinline__ float ldscalar(const void* p, int i, bool isf32) {
  return isf32 ? ((const float*)p)[i] : bf2f(((const u16*)p)[i]);
}

// ---------------------------------------------------------------------------
// Kc: fused convert of all 5 regions (4 elems/thread). Q-rows of Wqkv/bqkv
// (e%192 < 64) pre-scaled by QSCALE = 0.125*LOG2E (score lands in log2 units).
// ---------------------------------------------------------------------------
__global__ void convert_all(const void* __restrict__ x,  const void* __restrict__ wq,
                            const void* __restrict__ bq, const void* __restrict__ wo,
                            const void* __restrict__ bo,
                            u16* __restrict__ xd, u16* __restrict__ wqd,
                            u16* __restrict__ bqd, u16* __restrict__ wod,
                            u16* __restrict__ bod) {
  const bool f32in = sniff_f32((const u16*)x);
  const int b = blockIdx.x;
  const void* src; u16* dst; size_t base; int seg = 0;
  if (b < 4096)      { src = x;  dst = xd;  base = (size_t)b * 256; }
  else if (b < 7168) { src = wq; dst = wqd; base = (size_t)(b - 4096) * 256; seg = 1; }
  else if (b < 7171) { src = bq; dst = bqd; base = (size_t)(b - 7168) * 256; seg = 2; }
  else if (b < 8195) { src = wo; dst = wod; base = (size_t)(b - 7171) * 256; }
  else               { src = bo; dst = bod; base = 0; }
  const size_t i = base + threadIdx.x;
  float scale = 1.f;
  if (seg == 1) { const u32 row = (u32)(i >> 8); if (row % 192u < 64u) scale = QSCALE; }
  else if (seg == 2) { if (((u32)(i * 4)) % 192u < 64u) scale = QSCALE; }
  if (f32in) {
    const f32x4 a = ((const f32x4*)src)[i];
    u32 pb[4];
#pragma unroll
    for (int j = 0; j < 4; ++j) pb[j] = __float_as_uint(a[j] * scale) + 0x8000u;
    u32x2 o; o[0] = pack2bf(pb[0], pb[1]); o[1] = pack2bf(pb[2], pb[3]);
    ((u32x2*)dst)[i] = o;
  } else {
    u16x4 v = ((const u16x4*)src)[i];
    if (scale != 1.f) {
#pragma unroll
      for (int j = 0; j < 4; ++j) v[j] = f2bf(bf2f(v[j]) * scale);
    }
    ((u16x4*)dst)[i] = v;
  }
}

// ---------------------------------------------------------------------------
// NT-GEMM: C[m,n] = sum_k A[m,k]*Bw[n,k] (+bias). TM x 128 tile, BK=32,
// 4 waves in 2x2 (each TM/2 x 64). Register-prefetch + double-buffered LDS +
// one barrier/iter (flash-validated shape): iter i writes buf[i&1], issues
// tile i+1 loads (latency hides under barrier+compute), barrier, computes.
// Overwrite of buf[p] at iter i+2 is fenced by barrier(i+1).
// MODE 0 (TM=128): epilogue LDS-transpose -> coalesced Q/K/V^T stores.
// MODE 1: out[m,n] = val + bias[n], dtype per sniff.
// ---------------------------------------------------------------------------
template <int MODE, bool BPRE, int TM>
__global__ __launch_bounds__(256, 3) void gemm_nt(
    const u16* __restrict__ A, const void* __restrict__ Bw,
    const void* __restrict__ bias, int K, int N,
    void* __restrict__ out0, u16* __restrict__ out1, u16* __restrict__ out2,
    const u16* __restrict__ xsniff)
{
  constexpr int MI = TM / 32;                  // m-frags per wave
  constexpr int TILE = TM * 32;                // A-tile elems
  __shared__ __align__(16) u16 smem[2][TILE + 4096];   // [buf][A | B(128x32)]

  const bool f32in = sniff_f32(xsniff);
  const bool bw32  = BPRE ? false : f32in;

  const int tid  = threadIdx.x;
  const int wave = tid >> 6, lane = tid & 63;
  const int wm = wave >> 1, wn = wave & 1;
  const int fr = lane & 15, fq = lane >> 4;
  const int m0 = blockIdx.x * TM, n0 = blockIdx.y * 128;

  // staging map: thread t -> row t>>2 (0..63), cols (t&3)*8; +64-row pair for
  // the 128-deep operands (B always; A when TM=128)
  const int srow = tid >> 2, scol = (tid & 3) * 8;
  const int li   = srow * 32 + scol;
  const size_t eA = (size_t)(m0 + srow) * K + scol;
  const size_t eB = (size_t)(n0 + srow) * K + scol;
  const size_t half = (size_t)64 * K;

  f32x4 acc[MI][4];
#pragma unroll
  for (int i = 0; i < MI; ++i)
#pragma unroll
    for (int j = 0; j < 4; ++j) acc[i][j] = (f32x4){0.f, 0.f, 0.f, 0.f};

  // prologue: tile 0 into registers
  bf16x8 a0 = *(const bf16x8*)(A + eA);
  bf16x8 a1;
  if (TM == 128) a1 = *(const bf16x8*)(A + eA + half);
  bf16x8 b0 = ld8cv(Bw, eB, bw32);
  bf16x8 b1 = ld8cv(Bw, eB + half, bw32);

  for (int kt = 0; kt < K; kt += 32) {
    u16* As = smem[(kt >> 5) & 1];
    u16* Bs = As + TILE;
    // write tile kt (safe: fenced by barrier of iter kt-32)
    *(bf16x8*)(As + li) = a0;
    if (TM == 128) *(bf16x8*)(As + li + 2048) = a1;
    *(bf16x8*)(Bs + li) = b0;
    *(bf16x8*)(Bs + li + 2048) = b1;

    // prefetch tile kt+32 (guarded: last iter re-reads tile 0, unused)
    const int ktn = (kt + 32 < K) ? kt + 32 : 0;
    a0 = *(const bf16x8*)(A + eA + ktn);
    if (TM == 128) a1 = *(const bf16x8*)(A + eA + half + ktn);
    b0 = ld8cv(Bw, eB + ktn, bw32);
    b1 = ld8cv(Bw, eB + half + ktn, bw32);

    __syncthreads();                           // tile kt visible to all waves

    bf16x8 af[MI], bfv[4];
#pragma unroll
    for (int mi = 0; mi < MI; ++mi)
      af[mi] = *(const bf16x8*)(As + (wm * (TM / 2) + mi * 16 + fr) * 32 + fq * 8);
#pragma unroll
    for (int ni = 0; ni < 4; ++ni)
      bfv[ni] = *(const bf16x8*)(Bs + (wn * 64 + ni * 16 + fr) * 32 + fq * 8);
#pragma unroll
    for (int mi = 0; mi < MI; ++mi)
#pragma unroll
      for (int ni = 0; ni < 4; ++ni)
        acc[mi][ni] = __builtin_amdgcn_mfma_f32_16x16x32_bf16(af[mi], bfv[ni], acc[mi][ni], 0, 0, 0);
  }

  // C/D layout: row = fq*4 + r (m), col = fr (n)
  if (MODE == 0) {
    __syncthreads();                            // K-loop LDS reads done
    u16* swT = smem[0] + wave * 1152;           // 16 x 72 u16 wave scratch
    const int region = blockIdx.y * 2 + wn;     // e = region*64 + dk
    const int h = region / 3, which = region % 3;
    float bvv[4];
#pragma unroll
    for (int ni = 0; ni < 4; ++ni)
      bvv[ni] = ldscalar(bias, region * 64 + ni * 16 + fr, bw32);
    const float qs = BPRE ? 1.f : QSCALE;

    if (which < 2) {
      u16* outp = (which == 0) ? (u16*)out0 : out1;
      const float sc = (which == 0) ? qs : 1.f;
#pragma unroll
      for (int mi = 0; mi < MI; ++mi) {
#pragma unroll
        for (int ni = 0; ni < 4; ++ni)
#pragma unroll
          for (int r = 0; r < 4; ++r)
            swT[(fq * 4 + r) * 72 + ni * 16 + fr] = f2bf((acc[mi][ni][r] + bvv[ni]) * sc);
#pragma unroll
        for (int u = 0; u < 2; ++u) {
          const int idx = u * 64 + lane;
          const int m_l = idx >> 3, dkc = idx & 7;
          const bf16x8 row = *(const bf16x8*)(swT + m_l * 72 + dkc * 8);
          const int m = m0 + wm * (TM / 2) + mi * 16 + m_l;
          const int bb = m >> 11, s = m & 2047;
          *(bf16x8*)(outp + ((size_t)(bb * 16 + h) * 2048 + s) * 64 + dkc * 8) = row;
        }
      }
    } else {
#pragma unroll
      for (int ni = 0; ni < 4; ++ni) {
#pragma unroll
        for (int mi = 0; mi < MI; ++mi) {
          u16x4 pk;
#pragma unroll
          for (int r = 0; r < 4; ++r) pk[r] = f2bf(acc[mi][ni][r] + bvv[ni]);
          *(u16x4*)(swT + fr * 72 + mi * 16 + fq * 4) = pk;
        }
#pragma unroll
        for (int u = 0; u < 2; ++u) {
          const int idx = u * 64 + lane;
          const int dk_l = idx >> 3, mc = idx & 7;
          const bf16x8 row = *(const bf16x8*)(swT + dk_l * 72 + mc * 8);
          const int mb = m0 + wm * (TM / 2) + mc * 8;
          const int bb = mb >> 11, s0 = mb & 2047;
          *(bf16x8*)(out2 + ((size_t)((bb * 16 + h) * 64 + ni * 16 + dk_l)) * 2048 + s0) = row;
        }
      }
    }
  } else {
#pragma unroll
    for (int ni = 0; ni < 4; ++ni) {
      const int e = n0 + wn * 64 + ni * 16 + fr;
      const float bv = ldscalar(bias, e, bw32);
#pragma unroll
      for (int mi = 0; mi < MI; ++mi) {
#pragma unroll
        for (int r = 0; r < 4; ++r) {
          const int m = m0 + wm * (TM / 2) + mi * 16 + fq * 4 + r;
          const float v = acc[mi][ni][r] + bv;
          if (f32in) ((float*)out0)[(size_t)m * N + e] = v;
          else       ((u16*)out0)[(size_t)m * N + e]   = f2bf(v);
        }
      }
    }
  }
}

// ---------------------------------------------------------------------------
// K2: flash attention (unchanged from r12). grid (S/128, B*H), 4 waves,
// 32 q/wave. Fixed-shift softmax; XOR-swizzled LDS; double-buffered K/V
// (one barrier/iter); register K/V prefetch; l via ones-MFMA.
// ---------------------------------------------------------------------------
__global__ __launch_bounds__(256, 2) void flash_attn(
    const u16* __restrict__ Q, const u16* __restrict__ Kk,
    const u16* __restrict__ Vt, u16* __restrict__ AO)
{
  __shared__ __align__(16) u16 Kt[2][64 * 64];
  __shared__ __align__(16) u16 Vl[2][64 * 64];
  __shared__ __align__(16) u16 Plt[4 * 32 * 64];

  const int tid  = threadIdx.x;
  const int wave = tid >> 6, lane = tid & 63;
  const int fr = lane & 15, fq = lane >> 4;
  const int sw = fr & 7;                        // lane's XOR-swizzle key
  const int bh = blockIdx.y;
  const int q0 = blockIdx.x * 128;
  const size_t base = (size_t)bh * 2048 * 64;

  // all-ones bf16 A-fragment for the l-sum MFMA
  bf16x8 ones;
#pragma unroll
  for (int j = 0; j < 8; ++j) ones[j] = (short)0x3F80;

  // Q frags: qq in {0,1}; q = q0 + wave*32 + qq*16 + fr; d = fq*8+j (+32)
  bf16x8 qf[2][2];
#pragma unroll
  for (int qq = 0; qq < 2; ++qq) {
    const u16* qrow = Q + base + (size_t)(q0 + wave * 32 + qq * 16 + fr) * 64 + fq * 8;
    qf[qq][0] = *(const bf16x8*)(qrow);
    qf[qq][1] = *(const bf16x8*)(qrow + 32);
  }

  f32x4 oacc[2][4];                             // [qq][db]: d = db*16+fq*4+r, q(16) = fr
#pragma unroll
  for (int qq = 0; qq < 2; ++qq)
#pragma unroll
    for (int i = 0; i < 4; ++i) oacc[qq][i] = (f32x4){0.f, 0.f, 0.f, 0.f};
  f32x4 lD[2] = {(f32x4){0.f, 0.f, 0.f, 0.f}, (f32x4){0.f, 0.f, 0.f, 0.f}};

  // staging: thread t -> rows {t>>3, 32+(t>>3)}, logical chunk t&7, swizzled
  const int srow = tid >> 3, sc = tid & 7;
  const int so = srow * 64 + (sc ^ (srow & 7)) * 8;   // swizzled LDS offset
  const u16* gK = Kk + base + (size_t)srow * 64 + sc * 8;     // rows = keys
  const u16* gV = Vt + base + (size_t)srow * 2048 + sc * 8;   // rows = d
  u16* pw = Plt + wave * 32 * 64;               // per-wave P[q_local 0..31][key]

  // prologue: load tile 0
  bf16x8 k0 = *(const bf16x8*)(gK);
  bf16x8 k1 = *(const bf16x8*)(gK + 32 * 64);
  bf16x8 v0 = *(const bf16x8*)(gV);
  bf16x8 v1 = *(const bf16x8*)(gV + 32 * 2048);

  for (int kt = 0; kt < 32; ++kt) {
    u16* KtW = Kt[kt & 1];
    u16* VlW = Vl[kt & 1];
    // write tile kt into its buffer (safe: fenced by barrier of iter kt-1)
    *(bf16x8*)(KtW + so)           = k0;
    *(bf16x8*)(KtW + so + 32 * 64) = k1;        // row+32: same swizzle (&7 equal)
    *(bf16x8*)(VlW + so)           = v0;
    *(bf16x8*)(VlW + so + 32 * 64) = v1;

    // prefetch tile kt+1 (overruns at kt=31 stay inside d_ws; data unused)
    gK += 64 * 64;
    gV += 64;
    k0 = *(const bf16x8*)(gK);
    k1 = *(const bf16x8*)(gK + 32 * 64);
    v0 = *(const bf16x8*)(gV);
    v1 = *(const bf16x8*)(gV + 32 * 2048);

    __syncthreads();                            // tile kt visible to all waves

    // S^T = K Q^T; sacc init NSHIFT; p = 2^sacc directly
    f32x4 sacc[2][4];
#pragma unroll
    for (int qq = 0; qq < 2; ++qq)
#pragma unroll
      for (int cb = 0; cb < 4; ++cb)
        sacc[qq][cb] = (f32x4){NSHIFT, NSHIFT, NSHIFT, NSHIFT};
#pragma unroll
    for (int cb = 0; cb < 4; ++cb) {
      const u16* kr = KtW + (cb * 16 + fr) * 64;
      const int c0 = (fq ^ sw) * 8;             // logical chunk fq
      bf16x8 kf0 = *(const bf16x8*)(kr + c0);
      bf16x8 kf1 = *(const bf16x8*)(kr + (c0 ^ 32));   // logical chunk fq+4
#pragma unroll
      for (int qq = 0; qq < 2; ++qq) {
        sacc[qq][cb] = __builtin_amdgcn_mfma_f32_16x16x32_bf16(kf0, qf[qq][0], sacc[qq][cb], 0, 0, 0);
        sacc[qq][cb] = __builtin_amdgcn_mfma_f32_16x16x32_bf16(kf1, qf[qq][1], sacc[qq][cb], 0, 0, 0);
      }
    }

    // p = 2^sacc (raw v_exp_f32); pack bf16 -> wave-local LDS (in-order DS)
#pragma unroll
    for (int qq = 0; qq < 2; ++qq) {
      const int prow = (qq * 16 + fr) * 64;
#pragma unroll
      for (int cb = 0; cb < 4; ++cb) {
        u32 pb[4];
#pragma unroll
        for (int r = 0; r < 4; ++r)
          pb[r] = __float_as_uint(EXP2(sacc[qq][cb][r])) + 0x8000u;
        u32x2 pk;
        pk[0] = pack2bf(pb[0], pb[1]);
        pk[1] = pack2bf(pb[2], pb[3]);
        // key offset cb*16 + fq*4 -> logical chunk 2cb+(fq>>1), intra (fq&1)*4
        const int ch = ((2 * cb + (fq >> 1)) ^ sw) * 8 + (fq & 1) * 4;
        *(u32x2*)(pw + prow + ch) = pk;
      }
    }

    // O^T += V^T P^T; l += ones P^T (key-sum on the MFMA pipe)
#pragma unroll
    for (int g = 0; g < 2; ++g) {
      const int pc = ((4 * g + fq) ^ sw) * 8;
      bf16x8 pf0 = *(const bf16x8*)(pw + fr * 64 + pc);
      bf16x8 pf1 = *(const bf16x8*)(pw + (16 + fr) * 64 + pc);
#pragma unroll
      for (int db = 0; db < 4; ++db) {
        bf16x8 vf = *(const bf16x8*)(VlW + (db * 16 + fr) * 64 + pc);
        oacc[0][db] = __builtin_amdgcn_mfma_f32_16x16x32_bf16(vf, pf0, oacc[0][db], 0, 0, 0);
        oacc[1][db] = __builtin_amdgcn_mfma_f32_16x16x32_bf16(vf, pf1, oacc[1][db], 0, 0, 0);
      }
      lD[0] = __builtin_amdgcn_mfma_f32_16x16x32_bf16(ones, pf0, lD[0], 0, 0, 0);
      lD[1] = __builtin_amdgcn_mfma_f32_16x16x32_bf16(ones, pf1, lD[1], 0, 0, 0);
    }
  }

  // epilogue per q-group: lD rows are identical copies of l[q=fr]
  const int b = bh >> 4, h = bh & 15;
#pragma unroll
  for (int qq = 0; qq < 2; ++qq) {
    const float inv = 1.0f / lD[qq][0];
    const int s = q0 + wave * 32 + qq * 16 + fr;
    u16* orow = AO + ((size_t)(b * 2048 + s)) * 1024 + h * 64;
#pragma unroll
    for (int db = 0; db < 4; ++db) {
      u16x4 ov;
#pragma unroll
      for (int r = 0; r < 4; ++r) ov[r] = f2bf(oacc[qq][db][r] * inv);
      *(u16x4*)(orow + db * 16 + fq * 4) = ov;
    }
  }
}

// ---------------------------------------------------------------------------
extern "C" void kernel_launch(void* const* d_in, const int* in_sizes, int n_in,
                              void* d_out, int out_size, void* d_ws, size_t ws_size,
                              hipStream_t stream) {
  const void* x    = d_in[0];   // [2,2048,1024]  fp32 or bf16 (sniffed)
  const void* Wqkv = d_in[1];   // [3072,1024]
  const void* bqkv = d_in[2];   // [3072]
  const void* Wo   = d_in[3];   // [1024,1024]
  const void* bo   = d_in[4];   // [1024]
  const u16* xs    = (const u16*)x;

  const size_t HEADS = 32, S = 2048, DK = 64;
  const size_t NQ = HEADS * S * DK;
  u16* Qs = (u16*)d_ws;                    // bf16 (0.125*LOG2E folded)
  u16* Ks = Qs + NQ;
  u16* Vt = Ks + NQ;                       // V^T [BH,DK,S]
  u16* XA = Vt + NQ;                       // x-bf16 during K1; AO after flash

  u16* Wqb = XA + 2 * S * 1024;
  u16* Wob = Wqb + 3145728;
  u16* bqb = Wob + 1048576;
  u16* bob = bqb + 3072;
  const size_t need_big = ((size_t)(bob + 1024) - (size_t)d_ws);
  const bool big = ws_size >= need_big;

  if (big) {
    convert_all<<<8196, 256, 0, stream>>>(x, Wqkv, bqkv, Wo, bo,
                                          XA, Wqb, bqb, Wob, bob);
    gemm_nt<0, true, 128><<<dim3(32, 24), 256, 0, stream>>>(XA, Wqb, bqb, 1024, 3072,
                                                            Qs, Ks, Vt, xs);
    flash_attn<<<dim3(16, 32), 256, 0, stream>>>(Qs, Ks, Vt, XA);
    gemm_nt<1, true, 64><<<dim3(64, 8), 256, 0, stream>>>(XA, Wob, bob, 1024, 1024,
                                                          d_out, nullptr, nullptr, xs);
  } else {
    convert_all<<<4096, 256, 0, stream>>>(x, Wqkv, bqkv, Wo, bo,
                                          XA, XA, XA, XA, XA);   // x only
    gemm_nt<0, false, 128><<<dim3(32, 24), 256, 0, stream>>>(XA, Wqkv, bqkv, 1024, 3072,
                                                             Qs, Ks, Vt, xs);
    flash_attn<<<dim3(16, 32), 256, 0, stream>>>(Qs, Ks, Vt, XA);
    gemm_nt<1, false, 64><<<dim3(64, 8), 256, 0, stream>>>(XA, Wo, bo, 1024, 1024,
                                                           d_out, nullptr, nullptr, xs);
  }
}